// Round 5
// baseline (627.535 us; speedup 1.0000x reference)
//
#include <hip/hip_runtime.h>

// ---------------------------------------------------------------------------
// attention-pool: score = relu((V*g) @ w1 + b1) . w2 + b2 ; softmax over h ;
// out = sum_h alpha * V.    g = diag(W) * K.
// b=64, h=2048, d=hid=512.  M = b*h = 131072 rows, K = 512, N = 512.
// ---------------------------------------------------------------------------

#define MASK_FILL (-4294967295.0f) /* -2^32 + 1 */

typedef __attribute__((ext_vector_type(4))) float f32x4;
typedef __attribute__((ext_vector_type(8))) short bf16x8;
typedef __attribute__((ext_vector_type(8))) unsigned short us8;

__device__ __forceinline__ unsigned short f2bf(float f) {
  union { float f; unsigned u; } x; x.f = f;
  unsigned r = x.u + 0x7FFFu + ((x.u >> 16) & 1u);
  return (unsigned short)(r >> 16);
}

// ---------------- prep: g[b][d] = K[b][d] * W[d][d] ------------------------
__global__ void prep_g(const float* __restrict__ K, const float* __restrict__ W,
                       float* __restrict__ g) {
  int i = blockIdx.x * 256 + threadIdx.x;   // 32768
  int d = i & 511;
  g[i] = K[i] * W[d * 513];
}

// ---------------- prep: w1 -> tiled, transposed, XOR-swizzled bf16 ---------
// layout: tile = colblk*8 + kt (32 tiles of 16KB). within tile, element
// (c in [0,128), k in [0,64)) at byte ((c*128 + k*2) ^ ((c&7)<<4)).
// value = bf16( w1[kt*64 + k][colblk*128 + c] ).
__global__ void prep_w1(const float* __restrict__ w1, unsigned short* __restrict__ w1p) {
  int u = blockIdx.x * 256 + threadIdx.x;   // 32768 threads, 8 elems each
  int tile = u >> 10;                       // 0..31
  int w = u & 1023;
  int j = w >> 7;                           // k-chunk 0..7 (8 k's each)
  int c = w & 127;
  int colblk = tile >> 3, kt = tile & 7;
  int col = colblk * 128 + c;
  us8 o;
#pragma unroll
  for (int i = 0; i < 8; ++i)
    o[i] = f2bf(w1[(kt * 64 + j * 8 + i) * 512 + col]);
  int off = (c * 128 + j * 16) ^ ((c & 7) << 4);
  *(us8*)((char*)w1p + tile * 16384 + off) = o;
}

// ---------------- main fused GEMM + epilogue -------------------------------
#if __has_builtin(__builtin_amdgcn_global_load_lds)
#define HAVE_GLL 1
__device__ __forceinline__ void gload_lds16(const void* gsrc, void* ldst) {
  __builtin_amdgcn_global_load_lds(
      (const __attribute__((address_space(1))) void*)gsrc,
      (__attribute__((address_space(3))) void*)ldst, 16, 0, 0);
}
#else
#define HAVE_GLL 0
#endif

__launch_bounds__(256, 2)
__global__ void gemm_score(const float* __restrict__ V,
                           const unsigned short* __restrict__ w1p,
                           const float* __restrict__ g,
                           const float* __restrict__ b1,
                           const float* __restrict__ w2,
                           float* __restrict__ part) {
  __shared__ char lds[65536];  // 2 x (A 16KB + B 16KB)
  const int tid = threadIdx.x;
  const int lane = tid & 63, wid = tid >> 6;
  const int wr = wid >> 1, wc = wid & 1;
  // XCD-aware swizzle (T1): hardware dispatches blockIdx round-robin over the
  // 8 XCDs; remap so each XCD owns a contiguous chunk of logical tiles. Then
  // the 4 colblk-blocks of one rowtile (sharing a 256KB A-panel of V) land on
  // the SAME XCD -> panel fetched from HBM once, served from that XCD's L2.
  // 4096 % 8 == 0 so the simple bijective form is exact.
  const int bx = (blockIdx.x & 7) * 512 + (blockIdx.x >> 3);
  const int colblk = bx & 3;
  const int rowtile = bx >> 2;
  const int growbase = rowtile * 128;        // global row base (fits int)
  const int bidx = growbase >> 11;           // batch index

  // A staging: each thread owns (row ar, k-half akh) of the 128x64 chunk
  const int ar = tid >> 1;
  const int akh = tid & 1;
  const float* vrow = V + (long)(growbase + ar) * 512 + akh * 32;
  const float* grow = g + bidx * 512 + akh * 32;

  f32x4 acc[4][4];
#pragma unroll
  for (int m = 0; m < 4; ++m)
#pragma unroll
    for (int n = 0; n < 4; ++n) acc[m][n] = (f32x4){0.f, 0.f, 0.f, 0.f};

  float4 va[8], ga[8];

  // ---- helpers as lambdas ----
  auto issueB = [&](int t, int p) {
    const char* src = (const char*)w1p + (colblk * 8 + t) * 16384;
    char* dstbase = lds + p * 32768 + 16384;
#pragma unroll
    for (int i = 0; i < 4; ++i) {
      int seg = wid * 4 + i;                 // 16 segs of 1KB
#if HAVE_GLL
      gload_lds16(src + (seg * 64 + lane) * 16, dstbase + seg * 1024);
#else
      *(us8*)(dstbase + seg * 1024 + lane * 16) =
          *(const us8*)(src + (seg * 64 + lane) * 16);
#endif
    }
  };
  auto loadA = [&](int t) {
    const float* vp = vrow + t * 64;
    const float* gp = grow + t * 64;
#pragma unroll
    for (int i = 0; i < 8; ++i) {
      va[i] = *(const float4*)(vp + i * 4);
      ga[i] = *(const float4*)(gp + i * 4);
    }
  };
  auto writeA = [&](int p) {
    char* abase = lds + p * 32768;
#pragma unroll
    for (int j = 0; j < 4; ++j) {
      float4 v0 = va[2 * j], v1 = va[2 * j + 1];
      float4 g0 = ga[2 * j], g1 = ga[2 * j + 1];
      us8 o;
      o[0] = f2bf(v0.x * g0.x); o[1] = f2bf(v0.y * g0.y);
      o[2] = f2bf(v0.z * g0.z); o[3] = f2bf(v0.w * g0.w);
      o[4] = f2bf(v1.x * g1.x); o[5] = f2bf(v1.y * g1.y);
      o[6] = f2bf(v1.z * g1.z); o[7] = f2bf(v1.w * g1.w);
      int off = (ar * 128 + akh * 64 + j * 16) ^ ((ar & 7) << 4);
      *(us8*)(abase + off) = o;
    }
  };
  auto compute = [&](int p) {
    const char* ab = lds + p * 32768;
    const char* bb = ab + 16384;
    const int rA = wr * 64 + (lane & 15);
    const int cB = wc * 64 + (lane & 15);
    const int kk = (lane >> 4) * 16;  // byte offset for k = (lane>>4)*8
#pragma unroll
    for (int ks = 0; ks < 2; ++ks) {
      bf16x8 af[4], bf[4];
#pragma unroll
      for (int m = 0; m < 4; ++m) {
        int r = rA + m * 16;
        af[m] = *(const bf16x8*)(ab + ((r * 128 + ks * 64 + kk) ^ ((r & 7) << 4)));
      }
#pragma unroll
      for (int n = 0; n < 4; ++n) {
        int c = cB + n * 16;
        bf[n] = *(const bf16x8*)(bb + ((c * 128 + ks * 64 + kk) ^ ((c & 7) << 4)));
      }
#pragma unroll
      for (int m = 0; m < 4; ++m)
#pragma unroll
        for (int n = 0; n < 4; ++n)
          acc[m][n] = __builtin_amdgcn_mfma_f32_16x16x32_bf16(af[m], bf[n], acc[m][n], 0, 0, 0);
    }
  };

  // ---- prologue ----
  issueB(0, 0);
  loadA(0);
  writeA(0);
  __syncthreads();

  int p = 0;
#pragma unroll 1
  for (int t = 0; t < 8; ++t) {
    if (t < 7) { issueB(t + 1, p ^ 1); loadA(t + 1); }
    compute(p);
    if (t < 7) writeA(p ^ 1);
    __syncthreads();
    p ^= 1;
  }

  // ---- epilogue: score partial = sum_cols relu(acc + b1) * w2 ----
  const int colb = colblk * 128 + wc * 64 + (lane & 15);
  float b1v[4], w2v[4];
#pragma unroll
  for (int n = 0; n < 4; ++n) {
    b1v[n] = b1[colb + n * 16];
    w2v[n] = w2[colb + n * 16];
  }
  float* slice = part + (colblk * 2 + wc) * 131072;
  const int rowb = growbase + wr * 64 + ((lane >> 4) << 2);
#pragma unroll
  for (int m = 0; m < 4; ++m) {
#pragma unroll
    for (int r = 0; r < 4; ++r) {
      float v0 = acc[m][0][r] + b1v[0]; v0 = v0 > 0.f ? v0 : 0.f;
      float v1 = acc[m][1][r] + b1v[1]; v1 = v1 > 0.f ? v1 : 0.f;
      float v2 = acc[m][2][r] + b1v[2]; v2 = v2 > 0.f ? v2 : 0.f;
      float v3 = acc[m][3][r] + b1v[3]; v3 = v3 > 0.f ? v3 : 0.f;
      float s = v0 * w2v[0] + v1 * w2v[1] + v2 * w2v[2] + v3 * w2v[3];
      s += __shfl_xor(s, 1, 64);
      s += __shfl_xor(s, 2, 64);
      s += __shfl_xor(s, 4, 64);
      s += __shfl_xor(s, 8, 64);
      if ((lane & 15) == 0) slice[rowb + m * 16 + r] = s;
    }
  }
}

// ---------------- softmax over h per batch ---------------------------------
__global__ void softmax_k(const float* __restrict__ part, const int* __restrict__ mask,
                          const float* __restrict__ b2, float* __restrict__ alpha) {
  const int b = blockIdx.x;
  const int tid = threadIdx.x;  // 256
  __shared__ float red[256];
  float sc[8];
  float b2v = b2[0];
  float mx = -3.4e38f;
#pragma unroll
  for (int i = 0; i < 8; ++i) {
    int idx = b * 2048 + tid + i * 256;
    float s = b2v;
#pragma unroll
    for (int q = 0; q < 8; ++q) s += part[q * 131072 + idx];
    if (mask[idx] != 0) s = MASK_FILL;
    sc[i] = s;
    mx = fmaxf(mx, s);
  }
  red[tid] = mx;
  __syncthreads();
  for (int s = 128; s > 0; s >>= 1) {
    if (tid < s) red[tid] = fmaxf(red[tid], red[tid + s]);
    __syncthreads();
  }
  mx = red[0];
  __syncthreads();
  float sum = 0.f;
#pragma unroll
  for (int i = 0; i < 8; ++i) {
    sc[i] = expf(sc[i] - mx);
    sum += sc[i];
  }
  red[tid] = sum;
  __syncthreads();
  for (int s = 128; s > 0; s >>= 1) {
    if (tid < s) red[tid] += red[tid + s];
    __syncthreads();
  }
  float inv = 1.0f / red[0];
#pragma unroll
  for (int i = 0; i < 8; ++i)
    alpha[b * 2048 + tid + i * 256] = sc[i] * inv;
}

// ---------------- weighted sum: out[b][d] = sum_h alpha * V ----------------
__global__ void wsum_k(const float* __restrict__ V, const float* __restrict__ alpha,
                       float* __restrict__ out) {
  const int blk = blockIdx.x;          // 512 = 64 batches * 8 d-chunks
  const int b = blk >> 3, ch = blk & 7;
  const int tid = threadIdx.x;         // 256
  const int q = tid & 15, hs = tid >> 4;
  float4 acc = {0.f, 0.f, 0.f, 0.f};
  for (int h = hs; h < 2048; h += 16) {
    float a = alpha[b * 2048 + h];
    const float4 v = *(const float4*)(V + (long)(b * 2048 + h) * 512 + ch * 64 + q * 4);
    acc.x += a * v.x; acc.y += a * v.y; acc.z += a * v.z; acc.w += a * v.w;
  }
  __shared__ float4 sh[256];
  sh[tid] = acc;
  __syncthreads();
  for (int s = 8; s > 0; s >>= 1) {
    if (hs < s) {
      float4 o = sh[tid + 16 * s];
      sh[tid].x += o.x; sh[tid].y += o.y; sh[tid].z += o.z; sh[tid].w += o.w;
    }
    __syncthreads();
  }
  if (tid < 16) *(float4*)(out + b * 512 + ch * 64 + tid * 4) = sh[tid];
}

// ---------------------------------------------------------------------------
extern "C" void kernel_launch(void* const* d_in, const int* in_sizes, int n_in,
                              void* d_out, int out_size, void* d_ws, size_t ws_size,
                              hipStream_t stream) {
  const float* K   = (const float*)d_in[0];
  const float* V   = (const float*)d_in[1];
  const int*  mask = (const int*)d_in[2];
  const float* W   = (const float*)d_in[3];
  const float* w1  = (const float*)d_in[4];
  const float* b1  = (const float*)d_in[5];
  const float* w2  = (const float*)d_in[6];
  const float* b2  = (const float*)d_in[7];
  float* out = (float*)d_out;

  char* ws = (char*)d_ws;
  unsigned short* w1p = (unsigned short*)ws;       // 512 KB
  float* g     = (float*)(ws + 524288);            // 128 KB
  float* part  = (float*)(ws + 655360);            // 4 MB (8 slices x 131072)
  float* alpha = (float*)(ws + 4849664);           // 512 KB

  prep_g<<<128, 256, 0, stream>>>(K, W, g);
  prep_w1<<<128, 256, 0, stream>>>(w1, w1p);
  gemm_score<<<4096, 256, 0, stream>>>(V, w1p, g, b1, w2, part);
  softmax_k<<<64, 256, 0, stream>>>(part, mask, b2, alpha);
  wsum_k<<<512, 256, 0, stream>>>(V, alpha, out);
}